// Round 1
// baseline (1044.021 us; speedup 1.0000x reference)
//
#include <hip/hip_runtime.h>
#include <math.h>

#define NPTS 40000
#define KNB 16
#define CH 128

__device__ __forceinline__ float gelu_f(float v) {
  // jax.nn.gelu approximate=True (tanh form)
  float u = 0.7978845608028654f * (v + 0.044715f * v * v * v);
  return 0.5f * v * (1.0f + tanhf(u));
}

__device__ __forceinline__ float bnscale(float g) {
  return g * rsqrtf(1.0f + 1e-5f);
}

// ---------------- knn_spse_4 + BN0 ----------------
// one block per point, thread = channel
__global__ __launch_bounds__(128) void spse_kernel(
    const float* __restrict__ x, const float* __restrict__ xyz,
    const int* __restrict__ knn, const float* __restrict__ sm,
    const float* __restrict__ sc, const float* __restrict__ sh,
    const float* __restrict__ g0, const float* __restrict__ b0,
    float* __restrict__ out) {
  const int n = blockIdx.x;
  const int c = threadIdx.x;
  __shared__ float sr[KNB][3];
  __shared__ float sf[KNB][4];
  if (c < KNB) {
    const int j = knn[n * KNB + c];
    sr[c][0] = xyz[j * 3 + 0] - xyz[n * 3 + 0];
    sr[c][1] = xyz[j * 3 + 1] - xyz[n * 3 + 1];
    sr[c][2] = xyz[j * 3 + 2] - xyz[n * 3 + 2];
    float f0 = x[j * 4 + 0] - x[n * 4 + 0];
    float f1 = x[j * 4 + 1] - x[n * 4 + 1];
    float f2 = x[j * 4 + 2] - x[n * 4 + 2];
    float f3 = x[j * 4 + 3] - x[n * 4 + 3];
    sf[c][0] = f0 * f0; sf[c][1] = f1 * f1;
    sf[c][2] = f2 * f2; sf[c][3] = f3 * f3;
  }
  __syncthreads();
  const float m0 = sm[c], m1 = sm[CH + c], m2 = sm[2 * CH + c];
  const float m4 = sm[4 * CH + c], m5 = sm[5 * CH + c], m6 = sm[6 * CH + c];
  const float m8 = sm[8 * CH + c], m9 = sm[9 * CH + c], m10 = sm[10 * CH + c];
  float c0 = sc[c];          c0 *= c0;
  float c1 = sc[CH + c];     c1 *= c1;
  float c2 = sc[2 * CH + c]; c2 *= c2;
  float h2 = sh[c];          h2 *= h2;
  float e = 0.0f;
#pragma unroll
  for (int k = 0; k < KNB; k++) {
    const float r0 = sr[k][0], r1 = sr[k][1], r2 = sr[k][2];
    const float d0 = fmaf(r2, m2, fmaf(r1, m1, r0 * m0));
    const float d1 = fmaf(r2, m6, fmaf(r1, m5, r0 * m4));
    const float d2 = fmaf(r2, m10, fmaf(r1, m9, r0 * m8));
    e = fmaf(d0, d0, e);
    e = fmaf(d1, d1, e);
    e = fmaf(d2, d2, e);
    e = fmaf(sf[k][0], c0, e);
    e = fmaf(sf[k][1], c1, e);
    e = fmaf(sf[k][2], c2, e);
    e = fmaf(sf[k][3], h2, e);
  }
  const float v = sqrtf(e * (1.0f / KNB));
  out[(size_t)n * CH + c] = v * bnscale(g0[c]) + b0[c];
}

// ---------------- LFP gather + PE + max + BN + residual ----------------
__global__ __launch_bounds__(128) void lfp_kernel(
    const float* __restrict__ xp, const int* __restrict__ knn,
    const float* __restrict__ xyz, const float* __restrict__ coor,
    const float* __restrict__ scale, const float* __restrict__ g,
    const float* __restrict__ b, float* __restrict__ h) {
  const int n = blockIdx.x;
  const int c = threadIdx.x;
  __shared__ int si[KNB];
  __shared__ float sr[KNB][3];
  if (c < KNB) {
    const int j = knn[n * KNB + c];
    si[c] = j;
    sr[c][0] = xyz[j * 3 + 0] - xyz[n * 3 + 0];
    sr[c][1] = xyz[j * 3 + 1] - xyz[n * 3 + 1];
    sr[c][2] = xyz[j * 3 + 2] - xyz[n * 3 + 2];
  }
  __syncthreads();
  const int d = c >> 2;
  const float c0 = coor[d], c1 = coor[32 + d], c2 = coor[64 + d];
  float s2 = scale[d]; s2 *= s2;
  float acc = -3.0e38f;
#pragma unroll
  for (int k = 0; k < KNB; k++) {
    const float pe = fmaf(sr[k][2], c2, fmaf(sr[k][1], c1, sr[k][0] * c0)) * s2;
    acc = fmaxf(acc, xp[(size_t)si[k] * CH + c] + pe);
  }
  h[(size_t)n * CH + c] += acc * bnscale(g[c]) + b[c];
}

// ---------------- fold post-BN into post_w ----------------
__global__ __launch_bounds__(256) void fold_post(
    const float* __restrict__ w, const float* __restrict__ g,
    const float* __restrict__ b, float* __restrict__ fw,
    float* __restrict__ fb) {
  const int t = threadIdx.x;
  for (int idx = t; idx < 128 * 256; idx += 256) {
    const int cidx = idx >> 8;
    fw[idx] = w[idx] * bnscale(g[cidx]);
  }
  float acc = 0.0f;
  for (int cidx = 0; cidx < 128; cidx++)
    acc = fmaf(b[cidx], w[cidx * 256 + t], acc);
  fb[t] = acc;
}

// ---------------- fp32 GEMM: C = epi(A[MxK] @ B[KxN]) ----------------
// tile 128x128, BK=16, 256 threads, 8x8 micro-tile
// EPI: 0 none, 1 bias+gelu (p0), 2 BN (p0=g,p1=b), 3 BN+residual-add, 4 bias (p0)
template <int K, int EPI>
__global__ __launch_bounds__(256) void gemm128(
    const float* __restrict__ A, const float* __restrict__ B,
    const float* __restrict__ p0, const float* __restrict__ p1,
    float* __restrict__ C, int M, int N) {
  __shared__ float As[16][128];
  __shared__ float Bs[16][128];
  const int t = threadIdx.x;
  const int row0 = blockIdx.x * 128;
  const int col0 = blockIdx.y * 128;
  const int tm = t >> 4, tn = t & 15;
  const int lr = t >> 2, lc = (t & 3) << 2;   // A-tile load: 64 rows x (4 cols x4)
  const int br = t >> 4, bc = (t & 15) << 3;  // B-tile load: 16 rows x (16 cols x8)
  float acc[8][8];
#pragma unroll
  for (int i = 0; i < 8; i++)
#pragma unroll
    for (int j = 0; j < 8; j++) acc[i][j] = 0.0f;

  for (int kb = 0; kb < K; kb += 16) {
    int ra = row0 + lr;      if (ra >= M) ra = M - 1;
    int rb = row0 + lr + 64; if (rb >= M) rb = M - 1;
    const float4 a0 = *(const float4*)(A + (size_t)ra * K + kb + lc);
    const float4 a1 = *(const float4*)(A + (size_t)rb * K + kb + lc);
    const float4 b0 = *(const float4*)(B + (size_t)(kb + br) * N + col0 + bc);
    const float4 b1 = *(const float4*)(B + (size_t)(kb + br) * N + col0 + bc + 4);
    if (kb) __syncthreads();
    As[lc + 0][lr] = a0.x; As[lc + 1][lr] = a0.y;
    As[lc + 2][lr] = a0.z; As[lc + 3][lr] = a0.w;
    As[lc + 0][lr + 64] = a1.x; As[lc + 1][lr + 64] = a1.y;
    As[lc + 2][lr + 64] = a1.z; As[lc + 3][lr + 64] = a1.w;
    *(float4*)(&Bs[br][bc]) = b0;
    *(float4*)(&Bs[br][bc + 4]) = b1;
    __syncthreads();
#pragma unroll
    for (int k = 0; k < 16; k++) {
      const float4 a0v = *(const float4*)&As[k][tm * 8];
      const float4 a1v = *(const float4*)&As[k][tm * 8 + 4];
      const float4 b0v = *(const float4*)&Bs[k][tn * 8];
      const float4 b1v = *(const float4*)&Bs[k][tn * 8 + 4];
      const float av[8] = {a0v.x, a0v.y, a0v.z, a0v.w, a1v.x, a1v.y, a1v.z, a1v.w};
      const float bv[8] = {b0v.x, b0v.y, b0v.z, b0v.w, b1v.x, b1v.y, b1v.z, b1v.w};
#pragma unroll
      for (int i = 0; i < 8; i++)
#pragma unroll
        for (int j = 0; j < 8; j++) acc[i][j] = fmaf(av[i], bv[j], acc[i][j]);
    }
  }

#pragma unroll
  for (int i = 0; i < 8; i++) {
    const int r = row0 + tm * 8 + i;
    if (r >= M) continue;
    float* crow = C + (size_t)r * N + col0 + tn * 8;
#pragma unroll
    for (int jj = 0; jj < 8; jj += 4) {
      float vv[4];
#pragma unroll
      for (int q = 0; q < 4; q++) vv[q] = acc[i][jj + q];
      const int cg = col0 + tn * 8 + jj;
      if (EPI == 1) {
#pragma unroll
        for (int q = 0; q < 4; q++) vv[q] = gelu_f(vv[q] + p0[cg + q]);
      } else if (EPI == 2) {
#pragma unroll
        for (int q = 0; q < 4; q++) vv[q] = vv[q] * bnscale(p0[cg + q]) + p1[cg + q];
      } else if (EPI == 3) {
        const float4 old = *(const float4*)(crow + jj);
        const float ov[4] = {old.x, old.y, old.z, old.w};
#pragma unroll
        for (int q = 0; q < 4; q++)
          vv[q] = ov[q] + vv[q] * bnscale(p0[cg + q]) + p1[cg + q];
      } else if (EPI == 4) {
#pragma unroll
        for (int q = 0; q < 4; q++) vv[q] += p0[cg + q];
      }
      float4 o; o.x = vv[0]; o.y = vv[1]; o.z = vv[2]; o.w = vv[3];
      *(float4*)(crow + jj) = o;
    }
  }
}

extern "C" void kernel_launch(void* const* d_in, const int* in_sizes, int n_in,
                              void* d_out, int out_size, void* d_ws, size_t ws_size,
                              hipStream_t stream) {
  const float* x    = (const float*)d_in[0];
  const float* xyz  = (const float*)d_in[1];
  const int*   knn  = (const int*)d_in[2];
  const float* sm   = (const float*)d_in[3];
  const float* scc  = (const float*)d_in[4];
  const float* shh  = (const float*)d_in[5];
  const float* bn0g = (const float*)d_in[6];
  const float* bn0b = (const float*)d_in[7];
  const float* nw1  = (const float*)d_in[8];
  const float* nb1  = (const float*)d_in[9];
  const float* nw2  = (const float*)d_in[10];
  const float* nbng = (const float*)d_in[11];
  const float* nbnb = (const float*)d_in[12];
  const float* lproj  = (const float*)d_in[13];
  const float* lcoor  = (const float*)d_in[14];
  const float* lscale = (const float*)d_in[15];
  const float* lbng   = (const float*)d_in[16];
  const float* lbnb   = (const float*)d_in[17];
  const float* mw1  = (const float*)d_in[18];
  const float* mb1  = (const float*)d_in[19];
  const float* mw2  = (const float*)d_in[20];
  const float* mbng = (const float*)d_in[21];
  const float* mbnb = (const float*)d_in[22];
  const float* pg   = (const float*)d_in[23];
  const float* pb   = (const float*)d_in[24];
  const float* pw   = (const float*)d_in[25];
  float* out = (float*)d_out;

  float* W = (float*)d_ws;
  float* h    = W;                                // N x 128
  float* tbuf = W + (size_t)NPTS * 128;           // N x 512 (MLP hidden)
  float* xp   = tbuf + (size_t)NPTS * 256;        // N x 128 (aliased into tbuf's
                                                  //  upper half; never live together)
  float* fw   = W + (size_t)NPTS * 640;           // 128 x 256 folded post weights
  float* fb   = fw + 128 * 256;                   // 256 folded post bias

  const dim3 blk(256);
  const int gx = (NPTS + 127) / 128;  // 313

  // nbr = bn0(knn_spse4(...))  -> xp
  spse_kernel<<<NPTS, 128, 0, stream>>>(x, xyz, knn, sm, scc, shh, bn0g, bn0b, xp);
  // nbr_proj: gelu(xp @ w1 + b1) -> tbuf(Nx256); tbuf @ w2 -> bn -> h
  gemm128<128, 1><<<dim3(gx, 2), blk, 0, stream>>>(xp, nw1, nb1, nullptr, tbuf, NPTS, 256);
  gemm128<256, 2><<<dim3(gx, 1), blk, 0, stream>>>(tbuf, nw2, nbng, nbnb, h, NPTS, 128);
  // mlp 0 (residual)
  gemm128<128, 1><<<dim3(gx, 4), blk, 0, stream>>>(h, mw1, mb1, nullptr, tbuf, NPTS, 512);
  gemm128<512, 3><<<dim3(gx, 1), blk, 0, stream>>>(tbuf, mw2, mbng, mbnb, h, NPTS, 128);

  for (int i = 0; i < 4; i++) {
    gemm128<128, 0><<<dim3(gx, 1), blk, 0, stream>>>(h, lproj + (size_t)i * 128 * 128,
                                                     nullptr, nullptr, xp, NPTS, 128);
    lfp_kernel<<<NPTS, 128, 0, stream>>>(xp, knn, xyz, lcoor + i * 96, lscale + i * 32,
                                         lbng + i * 128, lbnb + i * 128, h);
    if (i & 1) {
      const int j = i / 2 + 1;
      gemm128<128, 1><<<dim3(gx, 4), blk, 0, stream>>>(
          h, mw1 + (size_t)j * 128 * 512, mb1 + j * 512, nullptr, tbuf, NPTS, 512);
      gemm128<512, 3><<<dim3(gx, 1), blk, 0, stream>>>(
          tbuf, mw2 + (size_t)j * 512 * 128, mbng + j * 128, mbnb + j * 128, h, NPTS, 128);
    }
  }

  // postproj: fold post-BN into weights, then GEMM with bias
  fold_post<<<1, 256, 0, stream>>>(pw, pg, pb, fw, fb);
  gemm128<128, 4><<<dim3(gx, 2), blk, 0, stream>>>(h, fw, fb, nullptr, out, NPTS, 256);
}

// Round 2
// 543.200 us; speedup vs baseline: 1.9220x; 1.9220x over previous
//
#include <hip/hip_runtime.h>
#include <hip/hip_bf16.h>
#include <math.h>

#define NPTS 40000
#define KNB 16
#define CH 128

typedef unsigned short u16;
typedef __attribute__((ext_vector_type(8))) short bf16x8;
typedef __attribute__((ext_vector_type(4))) float f32x4;

__device__ __forceinline__ float gelu_f(float v) {
  float u = 0.7978845608028654f * (v + 0.044715f * v * v * v);
  return 0.5f * v * (1.0f + tanhf(u));
}

__device__ __forceinline__ float bnscale(float g) {
  return g * rsqrtf(1.0f + 1e-5f);
}

__device__ __forceinline__ u16 f2bf(float x) {
  union { __hip_bfloat16 b; u16 u; } cv;
  cv.b = __float2bfloat16(x);
  return cv.u;
}

__device__ __forceinline__ float bf2f(u16 u) {
  union { float f; unsigned int i; } cv;
  cv.i = ((unsigned int)u) << 16;
  return cv.f;
}

__device__ __forceinline__ void bf16split(float x, u16& hi, u16& lo) {
  hi = f2bf(x);
  lo = f2bf(x - bf2f(hi));
}

// async global->LDS, 16B per lane, wave-uniform LDS base + lane*16
__device__ __forceinline__ void gl2lds(const u16* gp, u16* lp) {
  __builtin_amdgcn_global_load_lds(
      (const __attribute__((address_space(1))) void*)gp,
      (__attribute__((address_space(3))) void*)lp, 16, 0, 0);
}

// stage ROWS x 32 u16 tile (row-major, 64B rows) from g[grow0..][gcol0..gcol0+31]
template <int ROWS, bool CLAMP>
__device__ __forceinline__ void stage_tile(u16* lds, const u16* __restrict__ g,
                                           int gstride, int grow0, int gcol0,
                                           int t, int M) {
  const int w = t >> 6, lane = t & 63;
#pragma unroll
  for (int i = 0; i < ROWS * 4; i += 256) {
    const int wc0 = i + w * 64;          // wave-uniform chunk base
    const int c = wc0 + lane;            // this lane's 16B chunk
    int gr = grow0 + (c >> 2);
    if (CLAMP) gr = (gr < M) ? gr : (M - 1);
    const u16* gp = g + (size_t)gr * gstride + gcol0 + (c & 3) * 8;
    gl2lds(gp, lds + wc0 * 8);
  }
}

// ---------------- knn_spse_4 + BN0 -> bf16 hi/lo ----------------
__global__ __launch_bounds__(128) void spse_kernel(
    const float* __restrict__ x, const float* __restrict__ xyz,
    const int* __restrict__ knn, const float* __restrict__ sm,
    const float* __restrict__ sc, const float* __restrict__ sh,
    const float* __restrict__ g0, const float* __restrict__ b0,
    u16* __restrict__ oh, u16* __restrict__ ol) {
  const int n = blockIdx.x;
  const int c = threadIdx.x;
  __shared__ float sr[KNB][3];
  __shared__ float sf[KNB][4];
  if (c < KNB) {
    const int j = knn[n * KNB + c];
    sr[c][0] = xyz[j * 3 + 0] - xyz[n * 3 + 0];
    sr[c][1] = xyz[j * 3 + 1] - xyz[n * 3 + 1];
    sr[c][2] = xyz[j * 3 + 2] - xyz[n * 3 + 2];
    float f0 = x[j * 4 + 0] - x[n * 4 + 0];
    float f1 = x[j * 4 + 1] - x[n * 4 + 1];
    float f2 = x[j * 4 + 2] - x[n * 4 + 2];
    float f3 = x[j * 4 + 3] - x[n * 4 + 3];
    sf[c][0] = f0 * f0; sf[c][1] = f1 * f1;
    sf[c][2] = f2 * f2; sf[c][3] = f3 * f3;
  }
  __syncthreads();
  const float m0 = sm[c], m1 = sm[CH + c], m2 = sm[2 * CH + c];
  const float m4 = sm[4 * CH + c], m5 = sm[5 * CH + c], m6 = sm[6 * CH + c];
  const float m8 = sm[8 * CH + c], m9 = sm[9 * CH + c], m10 = sm[10 * CH + c];
  float c0 = sc[c];          c0 *= c0;
  float c1 = sc[CH + c];     c1 *= c1;
  float c2 = sc[2 * CH + c]; c2 *= c2;
  float h2 = sh[c];          h2 *= h2;
  float e = 0.0f;
#pragma unroll
  for (int k = 0; k < KNB; k++) {
    const float r0 = sr[k][0], r1 = sr[k][1], r2 = sr[k][2];
    const float d0 = fmaf(r2, m2, fmaf(r1, m1, r0 * m0));
    const float d1 = fmaf(r2, m6, fmaf(r1, m5, r0 * m4));
    const float d2 = fmaf(r2, m10, fmaf(r1, m9, r0 * m8));
    e = fmaf(d0, d0, e);
    e = fmaf(d1, d1, e);
    e = fmaf(d2, d2, e);
    e = fmaf(sf[k][0], c0, e);
    e = fmaf(sf[k][1], c1, e);
    e = fmaf(sf[k][2], c2, e);
    e = fmaf(sf[k][3], h2, e);
  }
  const float v = sqrtf(e * (1.0f / KNB)) * bnscale(g0[c]) + b0[c];
  u16 hi, lo; bf16split(v, hi, lo);
  const size_t idx = (size_t)n * CH + c;
  oh[idx] = hi; ol[idx] = lo;
}

// ---------------- LFP gather + PE + max + BN + residual (updates h + hi/lo) ----------------
__global__ __launch_bounds__(128) void lfp_kernel(
    const float* __restrict__ xp, const int* __restrict__ knn,
    const float* __restrict__ xyz, const float* __restrict__ coor,
    const float* __restrict__ scale, const float* __restrict__ g,
    const float* __restrict__ b, float* __restrict__ h,
    u16* __restrict__ hh, u16* __restrict__ hl) {
  const int n = blockIdx.x;
  const int c = threadIdx.x;
  __shared__ int si[KNB];
  __shared__ float sr[KNB][3];
  if (c < KNB) {
    const int j = knn[n * KNB + c];
    si[c] = j;
    sr[c][0] = xyz[j * 3 + 0] - xyz[n * 3 + 0];
    sr[c][1] = xyz[j * 3 + 1] - xyz[n * 3 + 1];
    sr[c][2] = xyz[j * 3 + 2] - xyz[n * 3 + 2];
  }
  __syncthreads();
  const int d = c >> 2;
  const float c0 = coor[d], c1 = coor[32 + d], c2 = coor[64 + d];
  float s2 = scale[d]; s2 *= s2;
  float acc = -3.0e38f;
#pragma unroll
  for (int k = 0; k < KNB; k++) {
    const float pe = fmaf(sr[k][2], c2, fmaf(sr[k][1], c1, sr[k][0] * c0)) * s2;
    acc = fmaxf(acc, xp[(size_t)si[k] * CH + c] + pe);
  }
  const size_t idx = (size_t)n * CH + c;
  const float nv = h[idx] + acc * bnscale(g[c]) + b[c];
  h[idx] = nv;
  u16 hi, lo; bf16split(nv, hi, lo);
  hh[idx] = hi; hl[idx] = lo;
}

// ---------------- weight prep: transpose + bf16 hi/lo split ----------------
// dst layout (u16 offsets): nw1@0(32768) nw2@32768 mw1[j]@65536+j*65536
// mw2[j]@262144+j*65536 lproj[i]@458752+i*16384 post@524288(32768)
__global__ __launch_bounds__(256) void prep_weights(
    const float* __restrict__ nw1, const float* __restrict__ nw2,
    const float* __restrict__ mw1, const float* __restrict__ mw2,
    const float* __restrict__ lproj, const float* __restrict__ pw,
    const float* __restrict__ pg, u16* __restrict__ th, u16* __restrict__ tl) {
  const int idx = blockIdx.x * 256 + threadIdx.x;
  const float* src;
  int local, Kd, Nd, dst;
  float scale = 1.0f;
  if (idx < 32768)        { src = nw1; local = idx;          Kd = 128; Nd = 256; dst = 0; }
  else if (idx < 65536)   { src = nw2; local = idx - 32768;  Kd = 256; Nd = 128; dst = 32768; }
  else if (idx < 262144)  { int j = (idx - 65536) >> 16;  local = (idx - 65536) & 65535;
                            src = mw1 + j * 65536; Kd = 128; Nd = 512; dst = 65536 + j * 65536; }
  else if (idx < 458752)  { int j = (idx - 262144) >> 16; local = (idx - 262144) & 65535;
                            src = mw2 + j * 65536; Kd = 512; Nd = 128; dst = 262144 + j * 65536; }
  else if (idx < 524288)  { int i = (idx - 458752) >> 14; local = (idx - 458752) & 16383;
                            src = lproj + i * 16384; Kd = 128; Nd = 128; dst = 458752 + i * 16384; }
  else if (idx < 557056)  { local = idx - 524288; src = pw; Kd = 128; Nd = 256; dst = 524288;
                            scale = bnscale(pg[local >> 8]); }
  else return;
  const int k = local / Nd, n = local % Nd;
  const float v = src[local] * scale;
  u16 hi, lo; bf16split(v, hi, lo);
  const int o = dst + n * Kd + k;
  th[o] = hi; tl[o] = lo;
}

// folded post bias: fb[n] = sum_k pb[k] * pw[k][n]  (unscaled W)
__global__ __launch_bounds__(256) void fold_pb(const float* __restrict__ pw,
                                               const float* __restrict__ pb,
                                               float* __restrict__ fb) {
  const int t = threadIdx.x;
  float a = 0.0f;
  for (int k = 0; k < 128; k++) a = fmaf(pb[k], pw[k * 256 + t], a);
  fb[t] = a;
}

// ---------------- split-bf16 MFMA GEMM ----------------
// C[M x N] = epi(A[M x K] @ B[K x N]); B pre-transposed as Bt[N][K] hi/lo.
// tile BM x 128, BK=32, 4 waves (2x2), 16x16x32 bf16 MFMA.
// EPI: 0 none, 1 bias+gelu(p0), 2 BN(p0,p1), 3 BN+residual, 4 bias(p0)
// EMIT: 0 none, 1 hi only, 2 hi+lo
template <int BM, int K, int EPI, int EMIT, bool WF32, bool HAS_ALO>
__global__ __launch_bounds__(256) void gemm_mfma(
    const u16* __restrict__ Ahi, const u16* __restrict__ Alo,
    const u16* __restrict__ Bth, const u16* __restrict__ Btl,
    const float* __restrict__ p0, const float* __restrict__ p1,
    float* __restrict__ Cf, u16* __restrict__ Chi, u16* __restrict__ Clo,
    int M, int N) {
  constexpr int MF = (BM == 128) ? 4 : 2;
  constexpr int NF = 4;
  constexpr bool CLAMP = (BM == 128);
  __shared__ __align__(16) u16 Ah[BM * 32];
  __shared__ __align__(16) u16 Al[HAS_ALO ? BM * 32 : 64];
  __shared__ __align__(16) u16 Bh[128 * 32];
  __shared__ __align__(16) u16 Bl[128 * 32];

  const int t = threadIdx.x;
  const int lane = t & 63;
  const int w = t >> 6;
  const int row0 = blockIdx.x * BM;
  const int col0 = blockIdx.y * 128;
  const int wm0 = (w >> 1) * (BM / 2);
  const int wn0 = (w & 1) * 64;
  const int lc = lane & 15;
  const int lq8 = (lane >> 4) * 8;

  const f32x4 zz = {0.0f, 0.0f, 0.0f, 0.0f};
  f32x4 acc[MF][NF];
#pragma unroll
  for (int mf = 0; mf < MF; mf++)
#pragma unroll
    for (int nf = 0; nf < NF; nf++) acc[mf][nf] = zz;

  for (int kb = 0; kb < K; kb += 32) {
    if (kb) __syncthreads();
    stage_tile<BM, CLAMP>(Ah, Ahi, K, row0, kb, t, M);
    if constexpr (HAS_ALO) stage_tile<BM, CLAMP>(Al, Alo, K, row0, kb, t, M);
    stage_tile<128, false>(Bh, Bth, K, col0, kb, t, M);
    stage_tile<128, false>(Bl, Btl, K, col0, kb, t, M);
    __syncthreads();

    bf16x8 af[MF], bhf[NF], blf[NF];
    bf16x8 alf[HAS_ALO ? MF : 1];
#pragma unroll
    for (int mf = 0; mf < MF; mf++) {
      const int rr = wm0 + mf * 16 + lc;
      af[mf] = *(const bf16x8*)(Ah + rr * 32 + lq8);
      if constexpr (HAS_ALO) alf[mf] = *(const bf16x8*)(Al + rr * 32 + lq8);
    }
#pragma unroll
    for (int nf = 0; nf < NF; nf++) {
      const int rr = wn0 + nf * 16 + lc;
      bhf[nf] = *(const bf16x8*)(Bh + rr * 32 + lq8);
      blf[nf] = *(const bf16x8*)(Bl + rr * 32 + lq8);
    }
#pragma unroll
    for (int mf = 0; mf < MF; mf++)
#pragma unroll
      for (int nf = 0; nf < NF; nf++) {
        acc[mf][nf] = __builtin_amdgcn_mfma_f32_16x16x32_bf16(af[mf], bhf[nf], acc[mf][nf], 0, 0, 0);
        acc[mf][nf] = __builtin_amdgcn_mfma_f32_16x16x32_bf16(af[mf], blf[nf], acc[mf][nf], 0, 0, 0);
        if constexpr (HAS_ALO)
          acc[mf][nf] = __builtin_amdgcn_mfma_f32_16x16x32_bf16(alf[mf], bhf[nf], acc[mf][nf], 0, 0, 0);
      }
  }

  // epilogue: C/D map: col = lane&15, row = (lane>>4)*4 + q
  float S0[NF], S1[NF];
#pragma unroll
  for (int nf = 0; nf < NF; nf++) {
    const int c = col0 + wn0 + nf * 16 + lc;
    if (EPI == 1 || EPI == 4) { S0[nf] = p0[c]; S1[nf] = 0.0f; }
    else if (EPI == 2 || EPI == 3) { S0[nf] = bnscale(p0[c]); S1[nf] = p1[c]; }
    else { S0[nf] = 0.0f; S1[nf] = 0.0f; }
  }
  const int lq4 = (lane >> 4) * 4;
#pragma unroll
  for (int mf = 0; mf < MF; mf++) {
#pragma unroll
    for (int q = 0; q < 4; q++) {
      const int r = row0 + wm0 + mf * 16 + lq4 + q;
      if (CLAMP && r >= M) continue;
#pragma unroll
      for (int nf = 0; nf < NF; nf++) {
        const int c = col0 + wn0 + nf * 16 + lc;
        const size_t off = (size_t)r * N + c;
        float v = acc[mf][nf][q];
        if (EPI == 1) v = gelu_f(v + S0[nf]);
        else if (EPI == 2) v = v * S0[nf] + S1[nf];
        else if (EPI == 3) v = Cf[off] + v * S0[nf] + S1[nf];
        else if (EPI == 4) v = v + S0[nf];
        if (WF32) Cf[off] = v;
        if (EMIT >= 1) {
          const u16 hb = f2bf(v);
          Chi[off] = hb;
          if (EMIT == 2) Clo[off] = f2bf(v - bf2f(hb));
        }
      }
    }
  }
}

extern "C" void kernel_launch(void* const* d_in, const int* in_sizes, int n_in,
                              void* d_out, int out_size, void* d_ws, size_t ws_size,
                              hipStream_t stream) {
  const float* x    = (const float*)d_in[0];
  const float* xyz  = (const float*)d_in[1];
  const int*   knn  = (const int*)d_in[2];
  const float* sm   = (const float*)d_in[3];
  const float* scc  = (const float*)d_in[4];
  const float* shh  = (const float*)d_in[5];
  const float* bn0g = (const float*)d_in[6];
  const float* bn0b = (const float*)d_in[7];
  const float* nw1  = (const float*)d_in[8];
  const float* nb1  = (const float*)d_in[9];
  const float* nw2  = (const float*)d_in[10];
  const float* nbng = (const float*)d_in[11];
  const float* nbnb = (const float*)d_in[12];
  const float* lproj  = (const float*)d_in[13];
  const float* lcoor  = (const float*)d_in[14];
  const float* lscale = (const float*)d_in[15];
  const float* lbng   = (const float*)d_in[16];
  const float* lbnb   = (const float*)d_in[17];
  const float* mw1  = (const float*)d_in[18];
  const float* mb1  = (const float*)d_in[19];
  const float* mw2  = (const float*)d_in[20];
  const float* mbng = (const float*)d_in[21];
  const float* mbnb = (const float*)d_in[22];
  const float* pg   = (const float*)d_in[23];
  const float* pb   = (const float*)d_in[24];
  const float* pw   = (const float*)d_in[25];
  float* out = (float*)d_out;

  // workspace layout (bytes)
  char* ws = (char*)d_ws;
  float* h    = (float*)(ws + 0);            // 40000*128*4  = 20,480,000
  u16*   h_hi = (u16*)(ws + 20480000);       // 40000*128*2  = 10,240,000
  u16*   h_lo = (u16*)(ws + 30720000);       // 10,240,000
  u16*   act  = (u16*)(ws + 40960000);       // 40000*512*2  = 40,960,000 (hid bf16 hi)
  float* xp   = (float*)(ws + 40960000);     // aliases act (never live together)
  u16*   Wh   = (u16*)(ws + 81920000);       // 557056*2 = 1,114,112
  u16*   Wl   = (u16*)(ws + 83034112);       // 1,114,112
  float* fb   = (float*)(ws + 84148224);     // 256*4

  const u16* nw1t   = Wh + 0;
  const u16* nw2t   = Wh + 32768;
  const u16* mw1t   = Wh + 65536;
  const u16* mw2t   = Wh + 262144;
  const u16* lprojt = Wh + 458752;
  const u16* postt  = Wh + 524288;
  const u16* nw1tl   = Wl + 0;
  const u16* nw2tl   = Wl + 32768;
  const u16* mw1tl   = Wl + 65536;
  const u16* mw2tl   = Wl + 262144;
  const u16* lprojtl = Wl + 458752;
  const u16* posttl  = Wl + 524288;

  prep_weights<<<2176, 256, 0, stream>>>(nw1, nw2, mw1, mw2, lproj, pw, pg, Wh, Wl);
  fold_pb<<<1, 256, 0, stream>>>(pw, pb, fb);

  // spse + BN0 -> nbr (bf16 hi/lo in h_hi/h_lo)
  spse_kernel<<<NPTS, 128, 0, stream>>>(x, xyz, knn, sm, scc, shh, bn0g, bn0b, h_hi, h_lo);

  // nbr_proj: gelu(nbr @ w1 + b1) -> act(40000x256, hi only); act @ w2 -> BN -> h(+hi/lo)
  gemm_mfma<128, 128, 1, 1, false, true><<<dim3(313, 2), 256, 0, stream>>>(
      h_hi, h_lo, nw1t, nw1tl, nb1, nullptr, nullptr, act, nullptr, NPTS, 256);
  gemm_mfma<64, 256, 2, 2, true, false><<<dim3(625, 1), 256, 0, stream>>>(
      act, nullptr, nw2t, nw2tl, nbng, nbnb, h, h_hi, h_lo, NPTS, 128);

  // mlp 0 (residual)
  gemm_mfma<128, 128, 1, 1, false, true><<<dim3(313, 4), 256, 0, stream>>>(
      h_hi, h_lo, mw1t, mw1tl, mb1, nullptr, nullptr, act, nullptr, NPTS, 512);
  gemm_mfma<64, 512, 3, 2, true, false><<<dim3(625, 1), 256, 0, stream>>>(
      act, nullptr, mw2t, mw2tl, mbng, mbnb, h, h_hi, h_lo, NPTS, 128);

  for (int i = 0; i < 4; i++) {
    // lfp proj: h @ proj -> xp (fp32)
    gemm_mfma<64, 128, 0, 0, true, true><<<dim3(625, 1), 256, 0, stream>>>(
        h_hi, h_lo, lprojt + i * 16384, lprojtl + i * 16384, nullptr, nullptr,
        xp, nullptr, nullptr, NPTS, 128);
    lfp_kernel<<<NPTS, 128, 0, stream>>>(xp, knn, xyz, lcoor + i * 96, lscale + i * 32,
                                         lbng + i * 128, lbnb + i * 128, h, h_hi, h_lo);
    if (i & 1) {
      const int j = i / 2 + 1;
      gemm_mfma<128, 128, 1, 1, false, true><<<dim3(313, 4), 256, 0, stream>>>(
          h_hi, h_lo, mw1t + j * 65536, mw1tl + j * 65536, mb1 + j * 512, nullptr,
          nullptr, act, nullptr, NPTS, 512);
      gemm_mfma<64, 512, 3, 2, true, false><<<dim3(625, 1), 256, 0, stream>>>(
          act, nullptr, mw2t + j * 65536, mw2tl + j * 65536, mbng + j * 128,
          mbnb + j * 128, h, h_hi, h_lo, NPTS, 128);
    }
  }

  // postproj: h @ folded(post_w) + folded bias -> out
  gemm_mfma<128, 128, 4, 0, true, true><<<dim3(313, 2), 256, 0, stream>>>(
      h_hi, h_lo, postt, posttl, fb, nullptr, out, nullptr, nullptr, NPTS, 256);
}